// Round 7
// baseline (233.227 us; speedup 1.0000x reference)
//
#include <hip/hip_runtime.h>
#include <stdint.h>

typedef __bf16 bf16_t;
typedef __bf16 bf16x8 __attribute__((ext_vector_type(8)));
typedef __bf16 bf16x4 __attribute__((ext_vector_type(4)));
typedef float floatx4 __attribute__((ext_vector_type(4)));

#define AS3(p) ((__attribute__((address_space(3))) void*)(p))
#define AS1(p) ((__attribute__((address_space(1))) void*)(void*)(p))

// ---------- fused prep: x f32->bf16, 4 weight transpose+converts ----------
__device__ __forceinline__ void tr_dev(const float* __restrict__ src, int ncols,
                                       bf16_t* __restrict__ dst, int bx, int by, int t,
                                       bf16_t (*T)[68]) {
  const int nt = bx * 64, kt = by * 64;
  const int r0 = t >> 4;         // 0..15
  const int c0 = (t & 15) << 2;  // 0..60
#pragma unroll
  for (int p = 0; p < 4; ++p) {
    const int row = p * 16 + r0;
    floatx4 v = *(const floatx4*)&src[(size_t)(kt + row) * ncols + nt + c0];
    bf16x4 b;
#pragma unroll
    for (int i = 0; i < 4; ++i) b[i] = (bf16_t)v[i];
    *(bf16x4*)&T[row][c0] = b;
  }
  __syncthreads();
#pragma unroll
  for (int p = 0; p < 4; ++p) {
    const int n = p * 16 + r0;
    bf16x4 tmp;
#pragma unroll
    for (int i = 0; i < 4; ++i) tmp[i] = T[c0 + i][n];
    *(bf16x4*)&dst[(size_t)(nt + n) * 2048 + kt + c0] = tmp;
  }
}

__global__ __launch_bounds__(256) void prep_k(const float* __restrict__ x,
                                              const float* __restrict__ wq,
                                              const float* __restrict__ wk,
                                              const float* __restrict__ wv,
                                              const float* __restrict__ wo,
                                              bf16_t* __restrict__ xb,
                                              bf16_t* __restrict__ wt) {
  __shared__ __align__(16) bf16_t T[64][68];
  const int b = blockIdx.x, tid = threadIdx.x;
  if (b < 2048) {  // cvt x: 2048 blocks x 2048 elems
    const int i = (b * 256 + tid) * 8;
    floatx4 a = *(const floatx4*)&x[i];
    floatx4 c = *(const floatx4*)&x[i + 4];
    bf16x8 o;
#pragma unroll
    for (int j = 0; j < 4; ++j) { o[j] = (bf16_t)a[j]; o[4 + j] = (bf16_t)c[j]; }
    *(bf16x8*)&xb[i] = o;
  } else if (b < 3072) {
    const int t = b - 2048;
    tr_dev(wq, 2048, wt, t & 31, t >> 5, tid, T);
  } else if (b < 3328) {
    const int t = b - 3072;
    tr_dev(wk, 512, wt + (size_t)2048 * 2048, t & 7, t >> 3, tid, T);
  } else if (b < 3584) {
    const int t = b - 3328;
    tr_dev(wv, 512, wt + (size_t)2560 * 2048, t & 7, t >> 3, tid, T);
  } else {
    const int t = b - 3584;
    tr_dev(wo, 2048, wt + (size_t)3072 * 2048, t & 31, t >> 5, tid, T);
  }
}

// ---------- GEMM: C[m][n] = sum_k A[m][k] * Bt[n][k], K=2048, A/Bt bf16 ----------
// Block = 64(M) x 128(N), 2 waves, each wave 64x64 (acc 4x4) — halves
// LDS-reads/FLOP vs R6's 64x32 waves (R6 was LDS-issue-bound: 12 b128 ~144cyc
// vs 16 MFMA ~78cyc). Grids stay exact multiples of 256 blocks (3/CU, 2/CU).
// Source-side chunk swizzle unchanged: LDS slot c^(r&7), read offset per-lane
// constant since fragment rows = l15 (mod 8).
template <int EPI>
__global__ __launch_bounds__(128) void gemm_k(const bf16_t* __restrict__ A,
                                              const bf16_t* __restrict__ Bt,
                                              bf16_t* __restrict__ o0,
                                              bf16_t* __restrict__ o1,
                                              bf16_t* __restrict__ o2,
                                              float* __restrict__ fo,
                                              const float* __restrict__ fcos,
                                              const float* __restrict__ fsin) {
  constexpr int K = 2048;
  __shared__ __align__(16) bf16_t As[64 * 64];
  __shared__ __align__(16) bf16_t Bs[128 * 64];
  const int tid = threadIdx.x;
  const int lane = tid & 63;
  const int w = tid >> 6;  // 0..1
  const int quad = lane >> 4;
  const int l15 = lane & 15;
  const int m0 = blockIdx.y * 64;
  const int n0 = blockIdx.x * 128;
  const int sr = lane >> 3;                      // 0..7
  const int sc = ((lane & 7) ^ (sr & 7)) << 3;   // swizzled source chunk
  const bf16_t* gA = A + (size_t)(m0 + w * 32 + sr) * K + sc;
  const bf16_t* gB = Bt + (size_t)(n0 + w * 64 + sr) * K + sc;
  bf16_t* lA = &As[(w * 32) * 64];
  bf16_t* lB = &Bs[(w * 64) * 64];
  floatx4 acc[4][4] = {};

  for (int k0 = 0; k0 < K; k0 += 64) {
#pragma unroll
    for (int j = 0; j < 4; ++j)
      __builtin_amdgcn_global_load_lds(AS1(gA + (size_t)j * 8 * K + k0),
                                       AS3(lA + j * 8 * 64), 16, 0, 0);
#pragma unroll
    for (int j = 0; j < 8; ++j)
      __builtin_amdgcn_global_load_lds(AS1(gB + (size_t)j * 8 * K + k0),
                                       AS3(lB + j * 8 * 64), 16, 0, 0);
    __syncthreads();
#pragma unroll
    for (int kk = 0; kk < 2; ++kk) {
      const int co = ((kk * 4 + quad) ^ (l15 & 7)) << 3;  // per-lane const offset
      bf16x8 af[4], bfr[4];
#pragma unroll
      for (int i = 0; i < 4; ++i) {
        af[i] = *(const bf16x8*)&As[(i * 16 + l15) * 64 + co];
        bfr[i] = *(const bf16x8*)&Bs[(w * 64 + i * 16 + l15) * 64 + co];
      }
#pragma unroll
      for (int mi = 0; mi < 4; ++mi)
#pragma unroll
        for (int ni = 0; ni < 4; ++ni)
          acc[mi][ni] =
              __builtin_amdgcn_mfma_f32_16x16x32_bf16(af[mi], bfr[ni], acc[mi][ni], 0, 0, 0);
    }
    __syncthreads();
  }

  if constexpr (EPI == 0) {
#pragma unroll
    for (int ni = 0; ni < 4; ++ni) {
      const int col = n0 + w * 64 + ni * 16 + l15;
#pragma unroll
      for (int mi = 0; mi < 4; ++mi) {
        const int sb = m0 + mi * 16 + quad * 4;
        if (col < 2560) {  // uniform per wave (boundaries are multiples of 16)
          const int fi = (col & 63) >> 1;
#pragma unroll
          for (int r = 0; r < 4; ++r) {
            const float v = acc[mi][ni][r];
            const float prt = __shfl_xor(v, 1);  // partner column within rope pair
            const int s = sb + r;
            const float c = fcos[s * 32 + fi];
            const float sn = fsin[s * 32 + fi];
            const float ov = (col & 1) ? (prt * sn + v * c) : (v * c - prt * sn);
            if (col < 2048)
              o0[(size_t)s * 2048 + col] = (bf16_t)ov;
            else
              o1[(size_t)s * 512 + (col - 2048)] = (bf16_t)ov;
          }
        } else {
          // sigma permutation within the 32-aligned s-block:
          // logical (t=mi&1, qs=quad, r) -> storage quad*8 + (mi&1)*4 + r
          const int sp = (sb & ~31) | (quad * 8 + (mi & 1) * 4);
          bf16x4 pv;
#pragma unroll
          for (int r = 0; r < 4; ++r) pv[r] = (bf16_t)acc[mi][ni][r];
          *(bf16x4*)&o2[(size_t)(col - 2560) * 2048 + sp] = pv;
        }
      }
    }
  } else {
#pragma unroll
    for (int ni = 0; ni < 4; ++ni) {
      const int col = n0 + w * 64 + ni * 16 + l15;
#pragma unroll
      for (int mi = 0; mi < 4; ++mi) {
        const int sb = m0 + mi * 16 + quad * 4;
#pragma unroll
        for (int r = 0; r < 4; ++r) fo[(size_t)(sb + r) * 2048 + col] = acc[mi][ni][r];
      }
    }
  }
}

// ---------- flash attention, S^T formulation, LDS-staged K/V (unchanged from R5) ----------
__global__ __launch_bounds__(256) void attn_k(const bf16_t* __restrict__ qb_,
                                              const bf16_t* __restrict__ kb_,
                                              const bf16_t* __restrict__ vt_,
                                              bf16_t* __restrict__ ob_) {
  __shared__ __align__(16) bf16_t sm[2][8 * 512];
  const int lane = threadIdx.x & 63, w = threadIdx.x >> 6;
  const int quad = lane >> 4, l15 = lane & 15;
  const int h = blockIdx.y, g = h >> 2;
  const int qb = (gridDim.x - 1 - blockIdx.x) * 64;  // heavy blocks first
  const int qw = qb + w * 16;
  const int q = qw + l15;
  const bf16_t* qrow = qb_ + (size_t)q * 2048 + h * 64;
  const bf16x8 qf0 = *(const bf16x8*)(qrow + quad * 8);
  const bf16x8 qf1 = *(const bf16x8*)(qrow + 32 + quad * 8);
  floatx4 acc0 = {}, acc1 = {}, acc2 = {}, acc3 = {}, accl = {};
  const float SC = 0.125f * 1.44269504088896340736f;  // scale * log2(e)
  bf16x8 ones;
#pragma unroll
  for (int i = 0; i < 8; ++i) ones[i] = (bf16_t)1.0f;

  int kbB = qb - 1024;
  if (kbB < 0) kbB = 0;
  kbB &= ~31;
  const int nT = (qb + 64 - kbB) >> 5;  // block-level tile count
  int myS = qw - 1024;
  if (myS < 0) myS = 0;
  myS &= ~31;
  const int myE = qw + 16;

  const int lr = lane & 15, lc = lane >> 4;
  const bf16_t* gk = kb_ + (size_t)(kbB + (w >> 1) * 16 + lr) * 512 + g * 64 +
                     ((w & 1) * 4 + lc) * 8;
  const bf16_t* gv = vt_ + (size_t)(g * 64 + w * 16 + lr) * 2048 + kbB + lc * 8;

#define STAGE(bi, ti)                                                              \
  do {                                                                             \
    __builtin_amdgcn_global_load_lds(AS1(gk + (size_t)(ti) * (32 * 512)),          \
                                     AS3(&sm[bi][w * 512]), 16, 0, 0);             \
    __builtin_amdgcn_global_load_lds(AS1(gv + (size_t)(ti) * 32),                  \
                                     AS3(&sm[bi][(4 + w) * 512]), 16, 0, 0);       \
  } while (0)

#define MSK(pv, key)                                        \
  do {                                                      \
    if ((key) > q || (key) + 1024 < q) pv = -1.0e30f;       \
  } while (0)

  int kb = kbB;
  STAGE(0, 0);
  __syncthreads();
  for (int i = 0; i < nT; ++i, kb += 32) {
    if (i + 1 < nT) STAGE((i + 1) & 1, i + 1);
    if (kb >= myS && kb < myE) {  // wave-uniform
      const bf16_t* base = &sm[i & 1][(size_t)lane * 8];
      const bf16x8 k0 = *(const bf16x8*)(base);
      const bf16x8 k1 = *(const bf16x8*)(base + 512);
      const bf16x8 k2 = *(const bf16x8*)(base + 1024);
      const bf16x8 k3 = *(const bf16x8*)(base + 1536);
      const bf16x8 v0 = *(const bf16x8*)(base + 2048);
      const bf16x8 v1 = *(const bf16x8*)(base + 2560);
      const bf16x8 v2 = *(const bf16x8*)(base + 3072);
      const bf16x8 v3 = *(const bf16x8*)(base + 3584);
      floatx4 z0 = {}, z1 = {};
      z0 = __builtin_amdgcn_mfma_f32_16x16x32_bf16(k0, qf0, z0, 0, 0, 0);
      z0 = __builtin_amdgcn_mfma_f32_16x16x32_bf16(k1, qf1, z0, 0, 0, 0);
      z1 = __builtin_amdgcn_mfma_f32_16x16x32_bf16(k2, qf0, z1, 0, 0, 0);
      z1 = __builtin_amdgcn_mfma_f32_16x16x32_bf16(k3, qf1, z1, 0, 0, 0);
      float p0 = z0[0] * SC - 32.0f, p1 = z0[1] * SC - 32.0f;
      float p2 = z0[2] * SC - 32.0f, p3 = z0[3] * SC - 32.0f;
      float p4 = z1[0] * SC - 32.0f, p5 = z1[1] * SC - 32.0f;
      float p6 = z1[2] * SC - 32.0f, p7 = z1[3] * SC - 32.0f;
      if ((kb + 31 > qw) || (kb < qw - 1009)) {  // wave-uniform edge mask
        const int kq = kb + quad * 4;
        MSK(p0, kq + 0); MSK(p1, kq + 1); MSK(p2, kq + 2); MSK(p3, kq + 3);
        MSK(p4, kq + 16); MSK(p5, kq + 17); MSK(p6, kq + 18); MSK(p7, kq + 19);
      }
      bf16x8 pf;  // == P^T B-fragment directly (sigma-permuted V columns)
      pf[0] = (bf16_t)__builtin_amdgcn_exp2f(p0);
      pf[1] = (bf16_t)__builtin_amdgcn_exp2f(p1);
      pf[2] = (bf16_t)__builtin_amdgcn_exp2f(p2);
      pf[3] = (bf16_t)__builtin_amdgcn_exp2f(p3);
      pf[4] = (bf16_t)__builtin_amdgcn_exp2f(p4);
      pf[5] = (bf16_t)__builtin_amdgcn_exp2f(p5);
      pf[6] = (bf16_t)__builtin_amdgcn_exp2f(p6);
      pf[7] = (bf16_t)__builtin_amdgcn_exp2f(p7);
      accl = __builtin_amdgcn_mfma_f32_16x16x32_bf16(ones, pf, accl, 0, 0, 0);
      acc0 = __builtin_amdgcn_mfma_f32_16x16x32_bf16(v0, pf, acc0, 0, 0, 0);
      acc1 = __builtin_amdgcn_mfma_f32_16x16x32_bf16(v1, pf, acc1, 0, 0, 0);
      acc2 = __builtin_amdgcn_mfma_f32_16x16x32_bf16(v2, pf, acc2, 0, 0, 0);
      acc3 = __builtin_amdgcn_mfma_f32_16x16x32_bf16(v3, pf, acc3, 0, 0, 0);
    }
    __syncthreads();
  }
#undef STAGE
#undef MSK

  const float inv = 1.0f / accl[0];
  bf16_t* obase = ob_ + (size_t)q * 2048 + h * 64 + quad * 4;
  bf16x4 ov;
#pragma unroll
  for (int r = 0; r < 4; ++r) ov[r] = (bf16_t)(acc0[r] * inv);
  *(bf16x4*)(obase) = ov;
#pragma unroll
  for (int r = 0; r < 4; ++r) ov[r] = (bf16_t)(acc1[r] * inv);
  *(bf16x4*)(obase + 16) = ov;
#pragma unroll
  for (int r = 0; r < 4; ++r) ov[r] = (bf16_t)(acc2[r] * inv);
  *(bf16x4*)(obase + 32) = ov;
#pragma unroll
  for (int r = 0; r < 4; ++r) ov[r] = (bf16_t)(acc3[r] * inv);
  *(bf16x4*)(obase + 48) = ov;
}

extern "C" void kernel_launch(void* const* d_in, const int* in_sizes, int n_in, void* d_out,
                              int out_size, void* d_ws, size_t ws_size, hipStream_t stream) {
  (void)in_sizes;
  (void)n_in;
  (void)out_size;
  (void)ws_size;
  const float* x = (const float*)d_in[0];
  const float* wq = (const float*)d_in[1];
  const float* wk = (const float*)d_in[2];
  const float* wv = (const float*)d_in[3];
  const float* wo = (const float*)d_in[4];
  const float* fcos = (const float*)d_in[5];
  const float* fsin = (const float*)d_in[6];
  float* out = (float*)d_out;

  bf16_t* xb = (bf16_t*)d_ws;
  bf16_t* wt = xb + (size_t)2048 * 2048;
  bf16_t* qbuf = wt + (size_t)5120 * 2048;
  bf16_t* kbuf = qbuf + (size_t)2048 * 2048;
  bf16_t* vtb = kbuf + (size_t)2048 * 512;
  bf16_t* att = vtb + (size_t)512 * 2048;

  prep_k<<<4608, 256, 0, stream>>>(x, wq, wk, wv, wo, xb, wt);
  gemm_k<0><<<dim3(24, 32), 128, 0, stream>>>(xb, wt, qbuf, kbuf, vtb, nullptr, fcos, fsin);
  attn_k<<<dim3(32, 32), 256, 0, stream>>>(qbuf, kbuf, vtb, att);
  gemm_k<1><<<dim3(16, 32), 128, 0, stream>>>(att, wt + (size_t)3072 * 2048, nullptr, nullptr,
                                              nullptr, out, fcos, fsin);
}

// Round 8
// 232.989 us; speedup vs baseline: 1.0010x; 1.0010x over previous
//
#include <hip/hip_runtime.h>
#include <stdint.h>

typedef __bf16 bf16_t;
typedef __bf16 bf16x8 __attribute__((ext_vector_type(8)));
typedef __bf16 bf16x4 __attribute__((ext_vector_type(4)));
typedef float floatx4 __attribute__((ext_vector_type(4)));

#define AS3(p) ((__attribute__((address_space(3))) void*)(p))
#define AS1(p) ((__attribute__((address_space(1))) void*)(void*)(p))

// ---------- fused prep: x f32->bf16, 4 weight transpose+converts ----------
__device__ __forceinline__ void tr_dev(const float* __restrict__ src, int ncols,
                                       bf16_t* __restrict__ dst, int bx, int by, int t,
                                       bf16_t (*T)[68]) {
  const int nt = bx * 64, kt = by * 64;
  const int r0 = t >> 4;         // 0..15
  const int c0 = (t & 15) << 2;  // 0..60
#pragma unroll
  for (int p = 0; p < 4; ++p) {
    const int row = p * 16 + r0;
    floatx4 v = *(const floatx4*)&src[(size_t)(kt + row) * ncols + nt + c0];
    bf16x4 b;
#pragma unroll
    for (int i = 0; i < 4; ++i) b[i] = (bf16_t)v[i];
    *(bf16x4*)&T[row][c0] = b;
  }
  __syncthreads();
#pragma unroll
  for (int p = 0; p < 4; ++p) {
    const int n = p * 16 + r0;
    bf16x4 tmp;
#pragma unroll
    for (int i = 0; i < 4; ++i) tmp[i] = T[c0 + i][n];
    *(bf16x4*)&dst[(size_t)(nt + n) * 2048 + kt + c0] = tmp;
  }
}

__global__ __launch_bounds__(256) void prep_k(const float* __restrict__ x,
                                              const float* __restrict__ wq,
                                              const float* __restrict__ wk,
                                              const float* __restrict__ wv,
                                              const float* __restrict__ wo,
                                              bf16_t* __restrict__ xb,
                                              bf16_t* __restrict__ wt) {
  __shared__ __align__(16) bf16_t T[64][68];
  const int b = blockIdx.x, tid = threadIdx.x;
  if (b < 2048) {  // cvt x
    const int i = (b * 256 + tid) * 8;
    floatx4 a = *(const floatx4*)&x[i];
    floatx4 c = *(const floatx4*)&x[i + 4];
    bf16x8 o;
#pragma unroll
    for (int j = 0; j < 4; ++j) { o[j] = (bf16_t)a[j]; o[4 + j] = (bf16_t)c[j]; }
    *(bf16x8*)&xb[i] = o;
  } else if (b < 3072) {
    const int t = b - 2048;
    tr_dev(wq, 2048, wt, t & 31, t >> 5, tid, T);
  } else if (b < 3328) {
    const int t = b - 3072;
    tr_dev(wk, 512, wt + (size_t)2048 * 2048, t & 7, t >> 3, tid, T);
  } else if (b < 3584) {
    const int t = b - 3328;
    tr_dev(wv, 512, wt + (size_t)2560 * 2048, t & 7, t >> 3, tid, T);
  } else {
    const int t = b - 3584;
    tr_dev(wo, 2048, wt + (size_t)3072 * 2048, t & 31, t >> 5, tid, T);
  }
}

// ---------- GEMM: C[m][n] = sum_k A[m][k] * Bt[n][k], K=2048 ----------
// R6 skeleton (64x128 block, 4 waves, 768/512 grids = 3/2 per CU) + K-SPLIT
// WAVE PAIRS: waves (w, w^1) share N-half (w>>1)*64; wave (w&1) computes only
// its 32-wide K-chunk of each BK=64 block -> 8 ds_read_b128 per 16 MFMAs
// (R6: 12; R7's 64x64-wave attempt got 8 too but halved TLP and regressed).
// Pairs sum partials via LDS exchange (reusing Bs) after the k-loop.
template <int EPI>
__global__ __launch_bounds__(256) void gemm_k(const bf16_t* __restrict__ A,
                                              const bf16_t* __restrict__ Bt,
                                              bf16_t* __restrict__ o0,
                                              bf16_t* __restrict__ o1,
                                              bf16_t* __restrict__ o2,
                                              float* __restrict__ fo,
                                              const float* __restrict__ fcos,
                                              const float* __restrict__ fsin) {
  constexpr int K = 2048;
  __shared__ __align__(16) bf16_t As[64 * 64];
  __shared__ __align__(16) bf16_t Bs[128 * 64];
  const int tid = threadIdx.x;
  const int lane = tid & 63;
  const int w = tid >> 6;
  const int quad = lane >> 4;
  const int l15 = lane & 15;
  const int m0 = blockIdx.y * 64;
  const int n0 = blockIdx.x * 128;
  const int sr = lane >> 3;                     // 0..7
  const int sc = ((lane & 7) ^ (sr & 7)) << 3;  // swizzled source chunk
  const bf16_t* gA = A + (size_t)(m0 + w * 16 + sr) * K + sc;
  const bf16_t* gB = Bt + (size_t)(n0 + w * 32 + sr) * K + sc;
  bf16_t* lA = &As[w * 1024];
  bf16_t* lB = &Bs[w * 2048];
  const int co = (((w & 1) * 4 + quad) ^ (l15 & 7)) << 3;  // this wave's K-chunk
  const int nbase = (w >> 1) * 64;                         // this wave's N-half
  floatx4 acc[4][4] = {};

  for (int k0 = 0; k0 < K; k0 += 64) {
    __builtin_amdgcn_global_load_lds(AS1(gA + k0), AS3(lA), 16, 0, 0);
    __builtin_amdgcn_global_load_lds(AS1(gA + 8 * K + k0), AS3(lA + 512), 16, 0, 0);
#pragma unroll
    for (int j = 0; j < 4; ++j)
      __builtin_amdgcn_global_load_lds(AS1(gB + (size_t)j * 8 * K + k0),
                                       AS3(lB + j * 512), 16, 0, 0);
    __syncthreads();
    bf16x8 af[4], bfr[4];
#pragma unroll
    for (int i = 0; i < 4; ++i) {
      af[i] = *(const bf16x8*)&As[(i * 16 + l15) * 64 + co];
      bfr[i] = *(const bf16x8*)&Bs[(nbase + i * 16 + l15) * 64 + co];
    }
#pragma unroll
    for (int mi = 0; mi < 4; ++mi)
#pragma unroll
      for (int ni = 0; ni < 4; ++ni)
        acc[mi][ni] =
            __builtin_amdgcn_mfma_f32_16x16x32_bf16(af[mi], bfr[ni], acc[mi][ni], 0, 0, 0);
    __syncthreads();
  }

  // ----- K-half exchange: pair (w, w^1). kk=0 wave owns m-tiles {0,1}, gives
  // {2,3}; kk=1 owns {2,3}, gives {0,1}. 2 rounds through Bs (16 KB = 4x4 KB
  // regions), lane-linear b128, constant acc indices (no dynamic indexing).
  {
    float* xch = (float*)Bs;
    float* wp = xch + w * 1024 + lane * 4;
    const float* rp = xch + (w ^ 1) * 1024 + lane * 4;
#define XW(mi)                                                   \
  {                                                              \
    _Pragma("unroll") for (int ni = 0; ni < 4; ++ni)             \
        *(floatx4*)(wp + ni * 256) = acc[mi][ni];                \
  }
#define XR(mi)                                                   \
  {                                                              \
    _Pragma("unroll") for (int ni = 0; ni < 4; ++ni) {           \
      floatx4 t = *(const floatx4*)(rp + ni * 256);              \
      acc[mi][ni] += t;                                          \
    }                                                            \
  }
    if (w & 1) { XW(0); } else { XW(2); }
    __syncthreads();
    if (w & 1) { XR(2); } else { XR(0); }
    __syncthreads();
    if (w & 1) { XW(1); } else { XW(3); }
    __syncthreads();
    if (w & 1) { XR(3); } else { XR(1); }
#undef XW
#undef XR
  }

  // ----- epilogue: wave owns m-tiles {(w&1)*2, (w&1)*2+1} x its N-half -----
#define EPIA(mi)                                                                     \
  {                                                                                  \
    _Pragma("unroll") for (int ni = 0; ni < 4; ++ni) {                               \
      const int col = n0 + nbase + ni * 16 + l15;                                    \
      const int sb = m0 + (mi)*16 + quad * 4;                                        \
      if (col < 2560) {                                                              \
        const int fi = (col & 63) >> 1;                                              \
        _Pragma("unroll") for (int r = 0; r < 4; ++r) {                              \
          const float v = acc[mi][ni][r];                                            \
          const float prt = __shfl_xor(v, 1);                                        \
          const int s = sb + r;                                                      \
          const float c = fcos[s * 32 + fi];                                         \
          const float sn = fsin[s * 32 + fi];                                        \
          const float ov = (col & 1) ? (prt * sn + v * c) : (v * c - prt * sn);      \
          if (col < 2048) o0[(size_t)s * 2048 + col] = (bf16_t)ov;                   \
          else o1[(size_t)s * 512 + (col - 2048)] = (bf16_t)ov;                      \
        }                                                                            \
      } else {                                                                       \
        const int sp = (sb & ~31) | (quad * 8 + ((mi)&1) * 4);                       \
        bf16x4 pv;                                                                   \
        _Pragma("unroll") for (int r = 0; r < 4; ++r) pv[r] = (bf16_t)acc[mi][ni][r];\
        *(bf16x4*)&o2[(size_t)(col - 2560) * 2048 + sp] = pv;                        \
      }                                                                              \
    }                                                                                \
  }
#define EPIB(mi)                                                                     \
  {                                                                                  \
    _Pragma("unroll") for (int ni = 0; ni < 4; ++ni) {                               \
      const int col = n0 + nbase + ni * 16 + l15;                                    \
      const int sb = m0 + (mi)*16 + quad * 4;                                        \
      _Pragma("unroll") for (int r = 0; r < 4; ++r)                                  \
          fo[(size_t)(sb + r) * 2048 + col] = acc[mi][ni][r];                        \
    }                                                                                \
  }
  if constexpr (EPI == 0) {
    if (w & 1) { EPIA(2); EPIA(3); } else { EPIA(0); EPIA(1); }
  } else {
    if (w & 1) { EPIB(2); EPIB(3); } else { EPIB(0); EPIB(1); }
  }
#undef EPIA
#undef EPIB
}

// ---------- flash attention, S^T formulation, LDS-staged K/V (unchanged from R5) ----------
__global__ __launch_bounds__(256) void attn_k(const bf16_t* __restrict__ qb_,
                                              const bf16_t* __restrict__ kb_,
                                              const bf16_t* __restrict__ vt_,
                                              bf16_t* __restrict__ ob_) {
  __shared__ __align__(16) bf16_t sm[2][8 * 512];
  const int lane = threadIdx.x & 63, w = threadIdx.x >> 6;
  const int quad = lane >> 4, l15 = lane & 15;
  const int h = blockIdx.y, g = h >> 2;
  const int qb = (gridDim.x - 1 - blockIdx.x) * 64;  // heavy blocks first
  const int qw = qb + w * 16;
  const int q = qw + l15;
  const bf16_t* qrow = qb_ + (size_t)q * 2048 + h * 64;
  const bf16x8 qf0 = *(const bf16x8*)(qrow + quad * 8);
  const bf16x8 qf1 = *(const bf16x8*)(qrow + 32 + quad * 8);
  floatx4 acc0 = {}, acc1 = {}, acc2 = {}, acc3 = {}, accl = {};
  const float SC = 0.125f * 1.44269504088896340736f;  // scale * log2(e)
  bf16x8 ones;
#pragma unroll
  for (int i = 0; i < 8; ++i) ones[i] = (bf16_t)1.0f;

  int kbB = qb - 1024;
  if (kbB < 0) kbB = 0;
  kbB &= ~31;
  const int nT = (qb + 64 - kbB) >> 5;  // block-level tile count
  int myS = qw - 1024;
  if (myS < 0) myS = 0;
  myS &= ~31;
  const int myE = qw + 16;

  const int lr = lane & 15, lc = lane >> 4;
  const bf16_t* gk = kb_ + (size_t)(kbB + (w >> 1) * 16 + lr) * 512 + g * 64 +
                     ((w & 1) * 4 + lc) * 8;
  const bf16_t* gv = vt_ + (size_t)(g * 64 + w * 16 + lr) * 2048 + kbB + lc * 8;

#define STAGE(bi, ti)                                                              \
  do {                                                                             \
    __builtin_amdgcn_global_load_lds(AS1(gk + (size_t)(ti) * (32 * 512)),          \
                                     AS3(&sm[bi][w * 512]), 16, 0, 0);             \
    __builtin_amdgcn_global_load_lds(AS1(gv + (size_t)(ti) * 32),                  \
                                     AS3(&sm[bi][(4 + w) * 512]), 16, 0, 0);       \
  } while (0)

#define MSK(pv, key)                                        \
  do {                                                      \
    if ((key) > q || (key) + 1024 < q) pv = -1.0e30f;       \
  } while (0)

  int kb = kbB;
  STAGE(0, 0);
  __syncthreads();
  for (int i = 0; i < nT; ++i, kb += 32) {
    if (i + 1 < nT) STAGE((i + 1) & 1, i + 1);
    if (kb >= myS && kb < myE) {  // wave-uniform
      const bf16_t* base = &sm[i & 1][(size_t)lane * 8];
      const bf16x8 k0 = *(const bf16x8*)(base);
      const bf16x8 k1 = *(const bf16x8*)(base + 512);
      const bf16x8 k2 = *(const bf16x8*)(base + 1024);
      const bf16x8 k3 = *(const bf16x8*)(base + 1536);
      const bf16x8 v0 = *(const bf16x8*)(base + 2048);
      const bf16x8 v1 = *(const bf16x8*)(base + 2560);
      const bf16x8 v2 = *(const bf16x8*)(base + 3072);
      const bf16x8 v3 = *(const bf16x8*)(base + 3584);
      floatx4 z0 = {}, z1 = {};
      z0 = __builtin_amdgcn_mfma_f32_16x16x32_bf16(k0, qf0, z0, 0, 0, 0);
      z0 = __builtin_amdgcn_mfma_f32_16x16x32_bf16(k1, qf1, z0, 0, 0, 0);
      z1 = __builtin_amdgcn_mfma_f32_16x16x32_bf16(k2, qf0, z1, 0, 0, 0);
      z1 = __builtin_amdgcn_mfma_f32_16x16x32_bf16(k3, qf1, z1, 0, 0, 0);
      float p0 = z0[0] * SC - 32.0f, p1 = z0[1] * SC - 32.0f;
      float p2 = z0[2] * SC - 32.0f, p3 = z0[3] * SC - 32.0f;
      float p4 = z1[0] * SC - 32.0f, p5 = z1[1] * SC - 32.0f;
      float p6 = z1[2] * SC - 32.0f, p7 = z1[3] * SC - 32.0f;
      if ((kb + 31 > qw) || (kb < qw - 1009)) {  // wave-uniform edge mask
        const int kq = kb + quad * 4;
        MSK(p0, kq + 0); MSK(p1, kq + 1); MSK(p2, kq + 2); MSK(p3, kq + 3);
        MSK(p4, kq + 16); MSK(p5, kq + 17); MSK(p6, kq + 18); MSK(p7, kq + 19);
      }
      bf16x8 pf;  // == P^T B-fragment directly (sigma-permuted V columns)
      pf[0] = (bf16_t)__builtin_amdgcn_exp2f(p0);
      pf[1] = (bf16_t)__builtin_amdgcn_exp2f(p1);
      pf[2] = (bf16_t)__builtin_amdgcn_exp2f(p2);
      pf[3] = (bf16_t)__builtin_amdgcn_exp2f(p3);
      pf[4] = (bf16_t)__builtin_amdgcn_exp2f(p4);
      pf[5] = (bf16_t)__builtin_amdgcn_exp2f(p5);
      pf[6] = (bf16_t)__builtin_amdgcn_exp2f(p6);
      pf[7] = (bf16_t)__builtin_amdgcn_exp2f(p7);
      accl = __builtin_amdgcn_mfma_f32_16x16x32_bf16(ones, pf, accl, 0, 0, 0);
      acc0 = __builtin_amdgcn_mfma_f32_16x16x32_bf16(v0, pf, acc0, 0, 0, 0);
      acc1 = __builtin_amdgcn_mfma_f32_16x16x32_bf16(v1, pf, acc1, 0, 0, 0);
      acc2 = __builtin_amdgcn_mfma_f32_16x16x32_bf16(v2, pf, acc2, 0, 0, 0);
      acc3 = __builtin_amdgcn_mfma_f32_16x16x32_bf16(v3, pf, acc3, 0, 0, 0);
    }
    __syncthreads();
  }
#undef STAGE
#undef MSK

  const float inv = 1.0f / accl[0];
  bf16_t* obase = ob_ + (size_t)q * 2048 + h * 64 + quad * 4;
  bf16x4 ov;
#pragma unroll
  for (int r = 0; r < 4; ++r) ov[r] = (bf16_t)(acc0[r] * inv);
  *(bf16x4*)(obase) = ov;
#pragma unroll
  for (int r = 0; r < 4; ++r) ov[r] = (bf16_t)(acc1[r] * inv);
  *(bf16x4*)(obase + 16) = ov;
#pragma unroll
  for (int r = 0; r < 4; ++r) ov[r] = (bf16_t)(acc2[r] * inv);
  *(bf16x4*)(obase + 32) = ov;
#pragma unroll
  for (int r = 0; r < 4; ++r) ov[r] = (bf16_t)(acc3[r] * inv);
  *(bf16x4*)(obase + 48) = ov;
}

extern "C" void kernel_launch(void* const* d_in, const int* in_sizes, int n_in, void* d_out,
                              int out_size, void* d_ws, size_t ws_size, hipStream_t stream) {
  (void)in_sizes;
  (void)n_in;
  (void)out_size;
  (void)ws_size;
  const float* x = (const float*)d_in[0];
  const float* wq = (const float*)d_in[1];
  const float* wk = (const float*)d_in[2];
  const float* wv = (const float*)d_in[3];
  const float* wo = (const float*)d_in[4];
  const float* fcos = (const float*)d_in[5];
  const float* fsin = (const float*)d_in[6];
  float* out = (float*)d_out;

  bf16_t* xb = (bf16_t*)d_ws;
  bf16_t* wt = xb + (size_t)2048 * 2048;
  bf16_t* qbuf = wt + (size_t)5120 * 2048;
  bf16_t* kbuf = qbuf + (size_t)2048 * 2048;
  bf16_t* vtb = kbuf + (size_t)2048 * 512;
  bf16_t* att = vtb + (size_t)512 * 2048;

  prep_k<<<4608, 256, 0, stream>>>(x, wq, wk, wv, wo, xb, wt);
  gemm_k<0><<<dim3(24, 32), 256, 0, stream>>>(xb, wt, qbuf, kbuf, vtb, nullptr, fcos, fsin);
  attn_k<<<dim3(32, 32), 256, 0, stream>>>(qbuf, kbuf, vtb, att);
  gemm_k<1><<<dim3(16, 32), 256, 0, stream>>>(att, wt + (size_t)3072 * 2048, nullptr, nullptr,
                                              nullptr, out, fcos, fsin);
}

// Round 9
// 227.370 us; speedup vs baseline: 1.0258x; 1.0247x over previous
//
#include <hip/hip_runtime.h>
#include <stdint.h>

typedef __bf16 bf16_t;
typedef __bf16 bf16x8 __attribute__((ext_vector_type(8)));
typedef __bf16 bf16x4 __attribute__((ext_vector_type(4)));
typedef float floatx4 __attribute__((ext_vector_type(4)));

#define AS3(p) ((__attribute__((address_space(3))) void*)(p))
#define AS1(p) ((__attribute__((address_space(1))) void*)(void*)(p))

// ---------- fused prep: x f32->bf16, 4 weight transpose+converts ----------
__device__ __forceinline__ void tr_dev(const float* __restrict__ src, int ncols,
                                       bf16_t* __restrict__ dst, int bx, int by, int t,
                                       bf16_t (*T)[68]) {
  const int nt = bx * 64, kt = by * 64;
  const int r0 = t >> 4;         // 0..15
  const int c0 = (t & 15) << 2;  // 0..60
#pragma unroll
  for (int p = 0; p < 4; ++p) {
    const int row = p * 16 + r0;
    floatx4 v = *(const floatx4*)&src[(size_t)(kt + row) * ncols + nt + c0];
    bf16x4 b;
#pragma unroll
    for (int i = 0; i < 4; ++i) b[i] = (bf16_t)v[i];
    *(bf16x4*)&T[row][c0] = b;
  }
  __syncthreads();
#pragma unroll
  for (int p = 0; p < 4; ++p) {
    const int n = p * 16 + r0;
    bf16x4 tmp;
#pragma unroll
    for (int i = 0; i < 4; ++i) tmp[i] = T[c0 + i][n];
    *(bf16x4*)&dst[(size_t)(nt + n) * 2048 + kt + c0] = tmp;
  }
}

__global__ __launch_bounds__(256) void prep_k(const float* __restrict__ x,
                                              const float* __restrict__ wq,
                                              const float* __restrict__ wk,
                                              const float* __restrict__ wv,
                                              const float* __restrict__ wo,
                                              bf16_t* __restrict__ xb,
                                              bf16_t* __restrict__ wt) {
  __shared__ __align__(16) bf16_t T[64][68];
  const int b = blockIdx.x, tid = threadIdx.x;
  if (b < 2048) {  // cvt x
    const int i = (b * 256 + tid) * 8;
    floatx4 a = *(const floatx4*)&x[i];
    floatx4 c = *(const floatx4*)&x[i + 4];
    bf16x8 o;
#pragma unroll
    for (int j = 0; j < 4; ++j) { o[j] = (bf16_t)a[j]; o[4 + j] = (bf16_t)c[j]; }
    *(bf16x8*)&xb[i] = o;
  } else if (b < 3072) {
    const int t = b - 2048;
    tr_dev(wq, 2048, wt, t & 31, t >> 5, tid, T);
  } else if (b < 3328) {
    const int t = b - 3072;
    tr_dev(wk, 512, wt + (size_t)2048 * 2048, t & 7, t >> 3, tid, T);
  } else if (b < 3584) {
    const int t = b - 3328;
    tr_dev(wv, 512, wt + (size_t)2560 * 2048, t & 7, t >> 3, tid, T);
  } else {
    const int t = b - 3584;
    tr_dev(wo, 2048, wt + (size_t)3072 * 2048, t & 31, t >> 5, tid, T);
  }
}

// ---------- GEMM: C[m][n] = sum_k A[m][k] * Bt[n][k], K=2048 ----------
// R6 winner (64x128 block, 4 waves of 64x32, 768/512 grids = 3/2 per CU,
// source-side chunk swizzle) + LDS DOUBLE-BUFFER, one barrier/iter:
// barrier -> prefetch stage(i+1) into other buffer -> compute tile i.
// R6's single buffer drained the DMA immediately at the next barrier
// (prefetch distance 0); this gives one compute phase of overlap.
template <int EPI>
__global__ __launch_bounds__(256) void gemm_k(const bf16_t* __restrict__ A,
                                              const bf16_t* __restrict__ Bt,
                                              bf16_t* __restrict__ o0,
                                              bf16_t* __restrict__ o1,
                                              bf16_t* __restrict__ o2,
                                              float* __restrict__ fo,
                                              const float* __restrict__ fcos,
                                              const float* __restrict__ fsin) {
  constexpr int K = 2048;
  __shared__ __align__(16) bf16_t As[2][64 * 64];
  __shared__ __align__(16) bf16_t Bs[2][128 * 64];
  const int tid = threadIdx.x;
  const int lane = tid & 63;
  const int w = tid >> 6;
  const int quad = lane >> 4;
  const int l15 = lane & 15;
  const int m0 = blockIdx.y * 64;
  const int n0 = blockIdx.x * 128;
  const int sr = lane >> 3;                     // 0..7
  const int sc = ((lane & 7) ^ (sr & 7)) << 3;  // swizzled source chunk
  const bf16_t* gA = A + (size_t)(m0 + w * 16 + sr) * K + sc;
  const bf16_t* gB = Bt + (size_t)(n0 + w * 32 + sr) * K + sc;
  floatx4 acc[4][2] = {};

#define GSTAGE(bi, k0v)                                                            \
  do {                                                                             \
    __builtin_amdgcn_global_load_lds(AS1(gA + (k0v)), AS3(&As[bi][w * 1024]), 16,  \
                                     0, 0);                                        \
    __builtin_amdgcn_global_load_lds(AS1(gA + 8 * K + (k0v)),                      \
                                     AS3(&As[bi][w * 1024 + 512]), 16, 0, 0);      \
    _Pragma("unroll") for (int j = 0; j < 4; ++j)                                  \
        __builtin_amdgcn_global_load_lds(AS1(gB + (size_t)j * 8 * K + (k0v)),      \
                                         AS3(&Bs[bi][w * 2048 + j * 512]), 16, 0,  \
                                         0);                                       \
  } while (0)

  GSTAGE(0, 0);
  for (int i = 0; i < 32; ++i) {
    __syncthreads();  // drains stage(i); one compute phase after its issue
    if (i + 1 < 32) GSTAGE((i + 1) & 1, (i + 1) * 64);
    const bf16_t* as = As[i & 1];
    const bf16_t* bs = Bs[i & 1];
#pragma unroll
    for (int kk = 0; kk < 2; ++kk) {
      const int co = ((kk * 4 + quad) ^ (l15 & 7)) << 3;  // per-lane const offset
      bf16x8 af[4], bfr[2];
#pragma unroll
      for (int ii = 0; ii < 4; ++ii)
        af[ii] = *(const bf16x8*)&as[(ii * 16 + l15) * 64 + co];
#pragma unroll
      for (int ii = 0; ii < 2; ++ii)
        bfr[ii] = *(const bf16x8*)&bs[(w * 32 + ii * 16 + l15) * 64 + co];
#pragma unroll
      for (int mi = 0; mi < 4; ++mi)
#pragma unroll
        for (int ni = 0; ni < 2; ++ni)
          acc[mi][ni] =
              __builtin_amdgcn_mfma_f32_16x16x32_bf16(af[mi], bfr[ni], acc[mi][ni], 0, 0, 0);
    }
  }
#undef GSTAGE

  if constexpr (EPI == 0) {
#pragma unroll
    for (int ni = 0; ni < 2; ++ni) {
      const int col = n0 + w * 32 + ni * 16 + l15;
#pragma unroll
      for (int mi = 0; mi < 4; ++mi) {
        const int sb = m0 + mi * 16 + quad * 4;
        if (col < 2560) {  // uniform per wave (boundaries are multiples of 16)
          const int fi = (col & 63) >> 1;
#pragma unroll
          for (int r = 0; r < 4; ++r) {
            const float v = acc[mi][ni][r];
            const float prt = __shfl_xor(v, 1);  // partner column within rope pair
            const int s = sb + r;
            const float c = fcos[s * 32 + fi];
            const float sn = fsin[s * 32 + fi];
            const float ov = (col & 1) ? (prt * sn + v * c) : (v * c - prt * sn);
            if (col < 2048)
              o0[(size_t)s * 2048 + col] = (bf16_t)ov;
            else
              o1[(size_t)s * 512 + (col - 2048)] = (bf16_t)ov;
          }
        } else {
          // sigma permutation within the 32-aligned s-block
          const int sp = (sb & ~31) | (quad * 8 + (mi & 1) * 4);
          bf16x4 pv;
#pragma unroll
          for (int r = 0; r < 4; ++r) pv[r] = (bf16_t)acc[mi][ni][r];
          *(bf16x4*)&o2[(size_t)(col - 2560) * 2048 + sp] = pv;
        }
      }
    }
  } else {
#pragma unroll
    for (int ni = 0; ni < 2; ++ni) {
      const int col = n0 + w * 32 + ni * 16 + l15;
#pragma unroll
      for (int mi = 0; mi < 4; ++mi) {
        const int sb = m0 + mi * 16 + quad * 4;
#pragma unroll
        for (int r = 0; r < 4; ++r) fo[(size_t)(sb + r) * 2048 + col] = acc[mi][ni][r];
      }
    }
  }
}

// ---------- flash attention: 3-buffer never-drain pipeline ----------
// Raw s_barrier + manual vmcnt(2): waits only the OLDEST stage, keeping the
// 1-2 newer stages in flight across the barrier (what __syncthreads forbids
// via its vmcnt(0) drain). Safety: a wave's ds_reads of tile i-1 are consumed
// (lgkm-drained by compiler) before it reaches barrier(i); stage(i+2)
// overwrites that buffer only after every wave passed barrier(i).
__global__ __launch_bounds__(256) void attn_k(const bf16_t* __restrict__ qb_,
                                              const bf16_t* __restrict__ kb_,
                                              const bf16_t* __restrict__ vt_,
                                              bf16_t* __restrict__ ob_) {
  __shared__ __align__(16) bf16_t sm[3][8 * 512];
  const int lane = threadIdx.x & 63, w = threadIdx.x >> 6;
  const int quad = lane >> 4, l15 = lane & 15;
  const int h = blockIdx.y, g = h >> 2;
  const int qb = (gridDim.x - 1 - blockIdx.x) * 64;  // heavy blocks first
  const int qw = qb + w * 16;
  const int q = qw + l15;
  const bf16_t* qrow = qb_ + (size_t)q * 2048 + h * 64;
  const bf16x8 qf0 = *(const bf16x8*)(qrow + quad * 8);
  const bf16x8 qf1 = *(const bf16x8*)(qrow + 32 + quad * 8);
  floatx4 acc0 = {}, acc1 = {}, acc2 = {}, acc3 = {}, accl = {};
  const float SC = 0.125f * 1.44269504088896340736f;  // scale * log2(e)
  bf16x8 ones;
#pragma unroll
  for (int i = 0; i < 8; ++i) ones[i] = (bf16_t)1.0f;

  int kbB = qb - 1024;
  if (kbB < 0) kbB = 0;
  kbB &= ~31;
  const int nT = (qb + 64 - kbB) >> 5;  // block-level tile count (>= 2)
  int myS = qw - 1024;
  if (myS < 0) myS = 0;
  myS &= ~31;
  const int myE = qw + 16;

  const int lr = lane & 15, lc = lane >> 4;
  const bf16_t* gk = kb_ + (size_t)(kbB + (w >> 1) * 16 + lr) * 512 + g * 64 +
                     ((w & 1) * 4 + lc) * 8;
  const bf16_t* gv = vt_ + (size_t)(g * 64 + w * 16 + lr) * 2048 + kbB + lc * 8;

#define STAGE(bi_, ti)                                                             \
  do {                                                                             \
    __builtin_amdgcn_global_load_lds(AS1(gk + (size_t)(ti) * (32 * 512)),          \
                                     AS3(&sm[bi_][w * 512]), 16, 0, 0);            \
    __builtin_amdgcn_global_load_lds(AS1(gv + (size_t)(ti) * 32),                  \
                                     AS3(&sm[bi_][(4 + w) * 512]), 16, 0, 0);      \
  } while (0)

#define MSK(pv, key)                                        \
  do {                                                      \
    if ((key) > q || (key) + 1024 < q) pv = -1.0e30f;       \
  } while (0)

  int kb = kbB;
  STAGE(0, 0);
  STAGE(1, 1);  // nT >= 2 always
  int bi = 0;
  for (int i = 0; i < nT; ++i, kb += 32) {
    asm volatile("s_waitcnt vmcnt(2)" ::: "memory");  // oldest stage landed
    __builtin_amdgcn_s_barrier();
    asm volatile("" ::: "memory");
    int p2 = bi - 1;
    if (p2 < 0) p2 = 2;  // (i+2) % 3
    if (i + 2 < nT) STAGE(p2, i + 2);
    if (kb >= myS && kb < myE) {  // wave-uniform
      const bf16_t* base = &sm[bi][(size_t)lane * 8];
      const bf16x8 k0 = *(const bf16x8*)(base);
      const bf16x8 k1 = *(const bf16x8*)(base + 512);
      const bf16x8 k2 = *(const bf16x8*)(base + 1024);
      const bf16x8 k3 = *(const bf16x8*)(base + 1536);
      const bf16x8 v0 = *(const bf16x8*)(base + 2048);
      const bf16x8 v1 = *(const bf16x8*)(base + 2560);
      const bf16x8 v2 = *(const bf16x8*)(base + 3072);
      const bf16x8 v3 = *(const bf16x8*)(base + 3584);
      floatx4 z0 = {}, z1 = {};
      z0 = __builtin_amdgcn_mfma_f32_16x16x32_bf16(k0, qf0, z0, 0, 0, 0);
      z0 = __builtin_amdgcn_mfma_f32_16x16x32_bf16(k1, qf1, z0, 0, 0, 0);
      z1 = __builtin_amdgcn_mfma_f32_16x16x32_bf16(k2, qf0, z1, 0, 0, 0);
      z1 = __builtin_amdgcn_mfma_f32_16x16x32_bf16(k3, qf1, z1, 0, 0, 0);
      float p0 = z0[0] * SC - 32.0f, p1 = z0[1] * SC - 32.0f;
      float p2f = z0[2] * SC - 32.0f, p3 = z0[3] * SC - 32.0f;
      float p4 = z1[0] * SC - 32.0f, p5 = z1[1] * SC - 32.0f;
      float p6 = z1[2] * SC - 32.0f, p7 = z1[3] * SC - 32.0f;
      if ((kb + 31 > qw) || (kb < qw - 1009)) {  // wave-uniform edge mask
        const int kq = kb + quad * 4;
        MSK(p0, kq + 0); MSK(p1, kq + 1); MSK(p2f, kq + 2); MSK(p3, kq + 3);
        MSK(p4, kq + 16); MSK(p5, kq + 17); MSK(p6, kq + 18); MSK(p7, kq + 19);
      }
      bf16x8 pf;  // == P^T B-fragment directly (sigma-permuted V columns)
      pf[0] = (bf16_t)__builtin_amdgcn_exp2f(p0);
      pf[1] = (bf16_t)__builtin_amdgcn_exp2f(p1);
      pf[2] = (bf16_t)__builtin_amdgcn_exp2f(p2f);
      pf[3] = (bf16_t)__builtin_amdgcn_exp2f(p3);
      pf[4] = (bf16_t)__builtin_amdgcn_exp2f(p4);
      pf[5] = (bf16_t)__builtin_amdgcn_exp2f(p5);
      pf[6] = (bf16_t)__builtin_amdgcn_exp2f(p6);
      pf[7] = (bf16_t)__builtin_amdgcn_exp2f(p7);
      accl = __builtin_amdgcn_mfma_f32_16x16x32_bf16(ones, pf, accl, 0, 0, 0);
      acc0 = __builtin_amdgcn_mfma_f32_16x16x32_bf16(v0, pf, acc0, 0, 0, 0);
      acc1 = __builtin_amdgcn_mfma_f32_16x16x32_bf16(v1, pf, acc1, 0, 0, 0);
      acc2 = __builtin_amdgcn_mfma_f32_16x16x32_bf16(v2, pf, acc2, 0, 0, 0);
      acc3 = __builtin_amdgcn_mfma_f32_16x16x32_bf16(v3, pf, acc3, 0, 0, 0);
    }
    bi = (bi == 2) ? 0 : bi + 1;
  }
  asm volatile("s_waitcnt vmcnt(0)" ::: "memory");
#undef STAGE
#undef MSK

  const float inv = 1.0f / accl[0];
  bf16_t* obase = ob_ + (size_t)q * 2048 + h * 64 + quad * 4;
  bf16x4 ov;
#pragma unroll
  for (int r = 0; r < 4; ++r) ov[r] = (bf16_t)(acc0[r] * inv);
  *(bf16x4*)(obase) = ov;
#pragma unroll
  for (int r = 0; r < 4; ++r) ov[r] = (bf16_t)(acc1[r] * inv);
  *(bf16x4*)(obase + 16) = ov;
#pragma unroll
  for (int r = 0; r < 4; ++r) ov[r] = (bf16_t)(acc2[r] * inv);
  *(bf16x4*)(obase + 32) = ov;
#pragma unroll
  for (int r = 0; r < 4; ++r) ov[r] = (bf16_t)(acc3[r] * inv);
  *(bf16x4*)(obase + 48) = ov;
}

extern "C" void kernel_launch(void* const* d_in, const int* in_sizes, int n_in, void* d_out,
                              int out_size, void* d_ws, size_t ws_size, hipStream_t stream) {
  (void)in_sizes;
  (void)n_in;
  (void)out_size;
  (void)ws_size;
  const float* x = (const float*)d_in[0];
  const float* wq = (const float*)d_in[1];
  const float* wk = (const float*)d_in[2];
  const float* wv = (const float*)d_in[3];
  const float* wo = (const float*)d_in[4];
  const float* fcos = (const float*)d_in[5];
  const float* fsin = (const float*)d_in[6];
  float* out = (float*)d_out;

  bf16_t* xb = (bf16_t*)d_ws;
  bf16_t* wt = xb + (size_t)2048 * 2048;
  bf16_t* qbuf = wt + (size_t)5120 * 2048;
  bf16_t* kbuf = qbuf + (size_t)2048 * 2048;
  bf16_t* vtb = kbuf + (size_t)2048 * 512;
  bf16_t* att = vtb + (size_t)512 * 2048;

  prep_k<<<4608, 256, 0, stream>>>(x, wq, wk, wv, wo, xb, wt);
  gemm_k<0><<<dim3(24, 32), 256, 0, stream>>>(xb, wt, qbuf, kbuf, vtb, nullptr, fcos, fsin);
  attn_k<<<dim3(32, 32), 256, 0, stream>>>(qbuf, kbuf, vtb, att);
  gemm_k<1><<<dim3(16, 32), 256, 0, stream>>>(att, wt + (size_t)3072 * 2048, nullptr, nullptr,
                                              nullptr, out, fcos, fsin);
}